// Round 3
// baseline (444.013 us; speedup 1.0000x reference)
//
#include <hip/hip_runtime.h>
#include <math.h>

#define B_ 16
#define NAV_ 36
#define H_ 120
#define W_ 160
#define HID_ 512
#define PLANES (B_*NAV_)          // 576
#define PLANE_PX (H_*W_)          // 19200
#define CANVAS_H 360
#define CANVAS_W 1920
#define CANVAS_PX (CANVAS_H*CANVAS_W)  // 691200

// workspace offsets (in floats)
#define WS_NAV    0                                   // 576
#define WS_FATT   576                                 // 64
#define WS_KERN   640                                 // 28800
#define WS_TD     29440                               // 11059200
#define WS_CANVAS (WS_TD + PLANES*PLANE_PX)           // + 11059200
#define WS_POOL1  (WS_CANVAS + B_*CANVAS_PX)          // + 16*2*19*89
#define WS_VF     (WS_POOL1 + B_*2*19*89)             // + 576

__device__ __forceinline__ float sigmoidf_(float x) { return 1.f / (1.f + expf(-x)); }

// Fully register-resident 4-pixel 5x5 grouped-conv row update.
// Window: A|B|C float4s covering cols x0-4 .. x0+7; taps WT from LDS (static idx).
// NOTE: macro param must NOT be named 'w' — it would capture the '.w' member.
#define ROW_MAC(WT, A, Bv, C)                                                \
    a0 += WT[0]*A.z  + WT[1]*A.w  + WT[2]*Bv.x + WT[3]*Bv.y + WT[4]*Bv.z;    \
    a1 += WT[0]*A.w  + WT[1]*Bv.x + WT[2]*Bv.y + WT[3]*Bv.z + WT[4]*Bv.w;    \
    a2 += WT[0]*Bv.x + WT[1]*Bv.y + WT[2]*Bv.z + WT[3]*Bv.w + WT[4]*C.x;     \
    a3 += WT[0]*Bv.y + WT[1]*Bv.z + WT[2]*Bv.w + WT[3]*C.x  + WT[4]*C.y;

// ---------------------------------------------------------------------------
// Kernel 1: grouped conv1 -> total_depth (ws).  blockIdx.x==19 blocks do the
// tiny precompute (nav softmax, filt_attn MLP, per-sample dyn kernels).
// grid (20, 576), 256 threads.
// ---------------------------------------------------------------------------
__global__ __launch_bounds__(256)
void k_td(const float* __restrict__ d0, const float* __restrict__ d1,
          const float* __restrict__ conv1_w, const float* __restrict__ conv1_b,
          const float* __restrict__ wctx, const float* __restrict__ dw1,
          const float* __restrict__ db1, const float* __restrict__ dw2,
          const float* __restrict__ db2, const float* __restrict__ dynf,
          const float* __restrict__ numnav, float* __restrict__ ws)
{
    const int tid = threadIdx.x;
    const int plane = blockIdx.y;

    if (blockIdx.x == 19) {
        // ---- precompute path: only 16 blocks (one per batch) do work ----
        if (plane % NAV_) return;
        const int b = plane / NAV_;
        __shared__ float sh[128];
        __shared__ float sred[8];
        __shared__ float nv[36];
        __shared__ float nms[2];
        if (tid < 128) {
            float acc = db1[tid];
            for (int k = 0; k < HID_; ++k) acc += wctx[b*HID_ + k] * dw1[k*128 + tid];
            sh[tid] = fmaxf(acc, 0.f);
        }
        __syncthreads();
        if (tid < 4) {
            float acc = db2[tid];
            for (int j = 0; j < 128; ++j) acc += sh[j] * dw2[j*4 + tid];
            sred[tid] = acc;
        }
        __syncthreads();
        if (tid == 0) {
            float m = fmaxf(fmaxf(sred[0], sred[1]), fmaxf(sred[2], sred[3]));
            float e0 = expf(sred[0]-m), e1 = expf(sred[1]-m), e2 = expf(sred[2]-m), e3 = expf(sred[3]-m);
            float s = e0+e1+e2+e3;
            sred[4] = e0/s; sred[5] = e1/s; sred[6] = e2/s; sred[7] = e3/s;
            ws[WS_FATT + b*4+0] = sred[4]; ws[WS_FATT + b*4+1] = sred[5];
            ws[WS_FATT + b*4+2] = sred[6]; ws[WS_FATT + b*4+3] = sred[7];
        }
        __syncthreads();
        {
            const float fa0 = sred[4], fa1 = sred[5], fa2 = sred[6], fa3 = sred[7];
            for (int e = tid; e < 1800; e += 256) {
                float v = fa0*dynf[e] + fa1*dynf[1800+e] + fa2*dynf[3600+e] + fa3*dynf[5400+e];
                ws[WS_KERN + b*1800 + e] = v;
            }
        }
        if (tid < 36) nv[tid] = numnav[b*NAV_ + tid];
        __syncthreads();
        if (tid == 0) {
            float m = nv[0];
            for (int i = 1; i < 36; ++i) m = fmaxf(m, nv[i]);
            float s = 0.f;
            for (int i = 0; i < 36; ++i) s += expf(nv[i]-m);
            nms[0] = m; nms[1] = s;
        }
        __syncthreads();
        if (tid < 36) ws[WS_NAV + b*NAV_ + tid] = expf(nv[tid]-nms[0]) / nms[1];
        return;
    }

    // ---- conv1 path: weights in LDS, window in named float4 regs ----
    const int g = plane % NAV_;
    __shared__ float swt[50];
    if (tid < 50) swt[tid] = conv1_w[g*50 + tid];
    __syncthreads();

    const int task = blockIdx.x*256 + tid;
    if (task >= 4800) return;
    const int y = task / 40;
    const int c4 = task % 40;
    const int x0 = c4*4;
    const bool hasL = c4 > 0, hasR = c4 < 39;

    const float bias = conv1_b[g];
    float a0 = bias, a1 = bias, a2 = bias, a3 = bias;
    const float* p0 = d0 + (size_t)plane*PLANE_PX + x0;
    const float* p1 = d1 + (size_t)plane*PLANE_PX + x0;
    const float4 z4 = make_float4(0.f, 0.f, 0.f, 0.f);

    #pragma unroll
    for (int ky = 0; ky < 5; ++ky) {
        const int yy = y + ky - 2;
        const bool vy = (unsigned)yy < (unsigned)H_;
        const float* r0 = p0 + (vy ? yy : 0)*W_;
        const float* r1 = p1 + (vy ? yy : 0)*W_;
        float4 A0 = (vy && hasL) ? *(const float4*)(r0-4) : z4;
        float4 B0 =  vy          ? *(const float4*)(r0)   : z4;
        float4 C0 = (vy && hasR) ? *(const float4*)(r0+4) : z4;
        float4 A1 = (vy && hasL) ? *(const float4*)(r1-4) : z4;
        float4 B1 =  vy          ? *(const float4*)(r1)   : z4;
        float4 C1 = (vy && hasR) ? *(const float4*)(r1+4) : z4;
        const float* wr0 = &swt[ky*5];
        const float* wr1 = &swt[25 + ky*5];
        ROW_MAC(wr0, A0, B0, C0)
        ROW_MAC(wr1, A1, B1, C1)
    }
    *(float4*)(ws + WS_TD + (size_t)plane*PLANE_PX + y*W_ + x0) = make_float4(a0, a1, a2, a3);
}

// ---------------------------------------------------------------------------
// Kernel 2: dynamic grouped conv over (td*a, obj*a) -> canvas layout.
// grid (19, 576), 256 threads.
// ---------------------------------------------------------------------------
__global__ __launch_bounds__(256)
void k_dyn(const float* __restrict__ obj, float* __restrict__ ws)
{
    const int tid = threadIdx.x;
    const int plane = blockIdx.y;
    const int b = plane / NAV_;
    const int g = plane % NAV_;

    __shared__ float swt[50];
    __shared__ float sa[1];
    if (tid < 50) swt[tid] = ws[WS_KERN + plane*50 + tid];
    if (tid == 50) sa[0] = ws[WS_NAV + plane];
    __syncthreads();

    const int task = blockIdx.x*256 + tid;
    if (task >= 4800) return;
    const int y = task / 40;
    const int c4 = task % 40;
    const int x0 = c4*4;
    const bool hasL = c4 > 0, hasR = c4 < 39;

    float a0 = 0.f, a1 = 0.f, a2 = 0.f, a3 = 0.f;
    const float* pt = ws + WS_TD + (size_t)plane*PLANE_PX + x0;
    const float* po = obj + (size_t)plane*PLANE_PX + x0;
    const float4 z4 = make_float4(0.f, 0.f, 0.f, 0.f);

    #pragma unroll
    for (int ky = 0; ky < 5; ++ky) {
        const int yy = y + ky - 2;
        const bool vy = (unsigned)yy < (unsigned)H_;
        const float* r0 = pt + (vy ? yy : 0)*W_;
        const float* r1 = po + (vy ? yy : 0)*W_;
        float4 A0 = (vy && hasL) ? *(const float4*)(r0-4) : z4;
        float4 B0 =  vy          ? *(const float4*)(r0)   : z4;
        float4 C0 = (vy && hasR) ? *(const float4*)(r0+4) : z4;
        float4 A1 = (vy && hasL) ? *(const float4*)(r1-4) : z4;
        float4 B1 =  vy          ? *(const float4*)(r1)   : z4;
        float4 C1 = (vy && hasR) ? *(const float4*)(r1+4) : z4;
        const float* wr0 = &swt[ky*5];
        const float* wr1 = &swt[25 + ky*5];
        ROW_MAC(wr0, A0, B0, C0)
        ROW_MAC(wr1, A1, B1, C1)
    }
    const float a = sa[0];
    const int rowblk = 2 - g/12;
    const int colblk = g % 12;
    float* outp = ws + WS_CANVAS + (size_t)b*CANVAS_PX + (rowblk*H_ + y)*CANVAS_W + colblk*W_ + x0;
    *(float4*)outp = make_float4(a0*a, a1*a, a2*a, a3*a);
}

// ---------------------------------------------------------------------------
// Kernel 3: conv2_1 (k5, stride (5,7), dil 10) + avgpool3x3/3 -> pool1 (ws).
// One block per (b, version, pool-row a).  grid 608, 256 threads.
// Rolled canvas (version 1) is an index remap: col' = (col + 1760) % 1920.
// ---------------------------------------------------------------------------
__global__ __launch_bounds__(256)
void k_conv2a(const float* __restrict__ w21p, const float* __restrict__ b21p,
              float* __restrict__ ws)
{
    const int blk = blockIdx.x;          // (b*2+ver)*19 + a
    const int a = blk % 19;
    const int bv = blk / 19;
    const int ver = bv & 1;
    const int b = bv >> 1;
    const int coloff = ver ? (CANVAS_W - W_) : 0;   // 1760

    __shared__ float s1[3*267];
    __shared__ float swt[25];
    if (threadIdx.x < 25) swt[threadIdx.x] = w21p[threadIdx.x];
    __syncthreads();
    const float b21 = b21p[0];
    const float* cv = ws + WS_CANVAS + (size_t)b*CANVAS_PX;

    for (int px = threadIdx.x; px < 3*267; px += 256) {
        const int row = px / 267;
        const int v = px % 267;
        const int u = 3*a + row;
        float acc = b21;
        #pragma unroll
        for (int ky = 0; ky < 5; ++ky) {
            const float* rp = cv + (5*u + 10*ky)*CANVAS_W;
            #pragma unroll
            for (int kx = 0; kx < 5; ++kx) {
                int c = 7*v + 10*kx + coloff;
                if (c >= CANVAS_W) c -= CANVAS_W;
                acc += swt[ky*5+kx] * rp[c];
            }
        }
        s1[px] = acc;
    }
    __syncthreads();
    if (threadIdx.x < 89) {
        const int bb = threadIdx.x;
        float s = 0.f;
        #pragma unroll
        for (int i = 0; i < 3; ++i)
            #pragma unroll
            for (int j = 0; j < 3; ++j)
                s += s1[i*267 + 3*bb + j];
        ws[WS_POOL1 + blk*89 + bb] = s * (1.f/9.f);
    }
}

// ---------------------------------------------------------------------------
// Kernel 4: conv2_2 + avgpool(3,9)/3 + v2 roll + combine + flip + softmax/10
// + mask.  One block per batch.  grid 16, 256 threads.
// ---------------------------------------------------------------------------
__global__ __launch_bounds__(256)
void k_conv2b(const float* __restrict__ w22p, const float* __restrict__ b22p,
              const int* __restrict__ navidx, float* __restrict__ ws,
              float* __restrict__ out)
{
    const int b = blockIdx.x;
    __shared__ float p[2*19*89];
    __shared__ float s2[2*9*43];
    __shared__ float svf[36];
    __shared__ float sms[2];
    __shared__ float swt[9];

    for (int i = threadIdx.x; i < 2*19*89; i += 256)
        p[i] = ws[WS_POOL1 + (b*2)*19*89 + i];
    if (threadIdx.x < 9) swt[threadIdx.x] = w22p[threadIdx.x];
    const float b22 = b22p[0];
    __syncthreads();

    for (int t = threadIdx.x; t < 2*9*43; t += 256) {
        const int ver = t / 387;
        const int r = t % 387;
        const int pp = r / 43;
        const int q = r % 43;
        float acc = b22;
        #pragma unroll
        for (int i = 0; i < 3; ++i)
            #pragma unroll
            for (int j = 0; j < 3; ++j)
                acc += swt[i*3+j] * p[(ver*19 + (2*pp+i))*89 + 2*q + 2*j];
        s2[ver*387 + pp*43 + q] = acc;
    }
    __syncthreads();

    if (threadIdx.x < 36) {
        const int gg = threadIdx.x;
        const int io = 2 - gg/12;
        const int j  = gg % 12;
        const int j2 = (j + 1) % 12;
        float s = 0.f;
        #pragma unroll
        for (int ii = 0; ii < 3; ++ii)
            #pragma unroll
            for (int jj = 0; jj < 9; ++jj)
                s += s2[(3*io+ii)*43 + 3*j + jj] + s2[387 + (3*io+ii)*43 + 3*j2 + jj];
        svf[gg] = s * (0.5f/27.f);
    }
    __syncthreads();
    if (threadIdx.x == 0) {
        float m = svf[0];
        for (int i = 1; i < 36; ++i) m = fmaxf(m, svf[i]);
        float s = 0.f;
        for (int i = 0; i < 36; ++i) s += expf((svf[i]-m)*0.1f);
        sms[0] = m; sms[1] = s;
    }
    __syncthreads();
    if (threadIdx.x < 36) {
        const float v = expf((svf[threadIdx.x]-sms[0])*0.1f) / sms[1];
        ws[WS_VF + b*36 + threadIdx.x] = v;
        out[16384 + b*36 + threadIdx.x] = v;
    }
    if (threadIdx.x < 37) {
        const int j = threadIdx.x;
        float v = (j == 0) ? 1.f : 0.f;
        #pragma unroll
        for (int t = 0; t < 8; ++t)
            if (navidx[b*8+t] + 1 == j) v = 1.f;
        out[16960 + b*37 + j] = v;
    }
}

// ---------------------------------------------------------------------------
// Kernel 5: LSTM GEMM + pointwise.  Block = 2 units x 4 gates x 16 batches,
// k split over 32 lanes.  concat stored transposed in LDS (stride 20 to
// avoid 16-dword bank conflicts).  grid 256, 256 threads.
// ---------------------------------------------------------------------------
#define CT_STRIDE 20
__global__ __launch_bounds__(256)
void k_lstm(const float* __restrict__ wctx, const float* __restrict__ pre_action,
            const float* __restrict__ h0, const float* __restrict__ c0,
            const float* __restrict__ w_ih, const float* __restrict__ w_hh,
            const float* __restrict__ b_ih, const float* __restrict__ b_hh,
            const float* __restrict__ ws, float* __restrict__ out)
{
    __shared__ float cT[1096*CT_STRIDE];
    __shared__ float red[8*32*16];
    __shared__ float gatev[8][16];
    const int tid = threadIdx.x;

    for (int idx = tid; idx < 1096*16; idx += 256) {
        const int k = idx >> 4;
        const int bb = idx & 15;
        float v;
        if (k < 512)       v = wctx[bb*512 + k];
        else if (k < 548)  v = ws[WS_VF + bb*36 + (k-512)];
        else if (k < 552)  v = ws[WS_FATT + bb*4 + (k-548)];
        else if (k < 584)  v = pre_action[bb*32 + (k-552)];
        else               v = h0[bb*512 + (k-584)];
        cT[k*CT_STRIDE + bb] = v;
    }
    __syncthreads();

    const int rl = tid >> 5;      // 0..7 : (gate<<1) | unit_local
    const int lane = tid & 31;
    const int u0 = blockIdx.x*2;
    const int ul = rl & 1;
    const int gate = rl >> 1;
    const int r = u0 + ul + gate*512;

    float acc[16];
    #pragma unroll
    for (int i = 0; i < 16; ++i) acc[i] = 0.f;

    const float* wih_r = w_ih + (size_t)r*584;
    for (int k = lane; k < 584; k += 32) {
        const float wv = wih_r[k];
        const float* cp = cT + k*CT_STRIDE;
        #pragma unroll
        for (int i = 0; i < 16; ++i) acc[i] += wv*cp[i];
    }
    const float* whh_r = w_hh + (size_t)r*512;
    for (int k = lane; k < 512; k += 32) {
        const float wv = whh_r[k];
        const float* cp = cT + (584+k)*CT_STRIDE;
        #pragma unroll
        for (int i = 0; i < 16; ++i) acc[i] += wv*cp[i];
    }
    float* rp = red + (rl*32 + lane)*16;
    #pragma unroll
    for (int i = 0; i < 16; ++i) rp[i] = acc[i];
    __syncthreads();

    if (tid < 128) {
        const int rr = tid >> 4;
        const int bb = tid & 15;
        const int rrow = u0 + (rr & 1) + (rr >> 1)*512;
        float s = b_ih[rrow] + b_hh[rrow];
        for (int l = 0; l < 32; ++l) s += red[(rr*32 + l)*16 + bb];
        gatev[rr][bb] = s;
    }
    __syncthreads();

    if (tid < 32) {
        const int ul2 = tid >> 4;
        const int bb = tid & 15;
        const int u = u0 + ul2;
        const float gi = gatev[0+ul2][bb];
        const float gf = gatev[2+ul2][bb];
        const float gg = gatev[4+ul2][bb];
        const float go = gatev[6+ul2][bb];
        const float c1 = sigmoidf_(gf)*c0[bb*512+u] + sigmoidf_(gi)*tanhf(gg);
        const float h1 = sigmoidf_(go)*tanhf(c1);
        out[bb*512 + u] = h1;
        out[8192 + bb*512 + u] = c1;
    }
}

// ---------------------------------------------------------------------------
extern "C" void kernel_launch(void* const* d_in, const int* in_sizes, int n_in,
                              void* d_out, int out_size, void* d_ws, size_t ws_size,
                              hipStream_t stream)
{
    const float* d0        = (const float*)d_in[0];
    const float* d1        = (const float*)d_in[1];
    const float* obj       = (const float*)d_in[2];
    const float* numnav    = (const float*)d_in[3];
    const float* preact    = (const float*)d_in[4];
    const float* h0        = (const float*)d_in[5];
    const float* c0        = (const float*)d_in[6];
    const float* wctx      = (const float*)d_in[7];
    const int*   navidx    = (const int*)d_in[8];
    const float* conv1_w   = (const float*)d_in[9];
    const float* conv1_b   = (const float*)d_in[10];
    const float* dynf      = (const float*)d_in[11];
    const float* dw1       = (const float*)d_in[12];
    const float* db1       = (const float*)d_in[13];
    const float* dw2       = (const float*)d_in[14];
    const float* db2       = (const float*)d_in[15];
    const float* w21       = (const float*)d_in[16];
    const float* b21       = (const float*)d_in[17];
    const float* w22       = (const float*)d_in[18];
    const float* b22       = (const float*)d_in[19];
    const float* wih       = (const float*)d_in[20];
    const float* whh       = (const float*)d_in[21];
    const float* bih       = (const float*)d_in[22];
    const float* bhh       = (const float*)d_in[23];
    float* ws  = (float*)d_ws;
    float* out = (float*)d_out;

    dim3 blk(256);
    k_td    <<<dim3(20, 576), blk, 0, stream>>>(d0, d1, conv1_w, conv1_b, wctx,
                                                dw1, db1, dw2, db2, dynf, numnav, ws);
    k_dyn   <<<dim3(19, 576), blk, 0, stream>>>(obj, ws);
    k_conv2a<<<dim3(608),     blk, 0, stream>>>(w21, b21, ws);
    k_conv2b<<<dim3(16),      blk, 0, stream>>>(w22, b22, navidx, ws, out);
    k_lstm  <<<dim3(256),     blk, 0, stream>>>(wctx, preact, h0, c0, wih, whh,
                                                bih, bhh, ws, out);
}

// Round 4
// 261.793 us; speedup vs baseline: 1.6960x; 1.6960x over previous
//
#include <hip/hip_runtime.h>
#include <math.h>

#define B_ 16
#define NAV_ 36
#define H_ 120
#define W_ 160
#define HID_ 512
#define PLANES (B_*NAV_)          // 576
#define PLANE_PX (H_*W_)          // 19200
#define CANVAS_H 360
#define CANVAS_W 1920
#define CANVAS_PX (CANVAS_H*CANVAS_W)  // 691200

// fused-kernel tiling
#define OUT_H 20                  // output rows per band (120 = 6*20)
#define TD_ROWS (OUT_H+4)         // 24
#define IN_ROWS (OUT_H+8)         // 28
#define LSTR 164                  // padded LDS row stride (4 left-pad + 160)

// workspace offsets (in floats)
#define WS_NAV    0                                   // 576
#define WS_FATT   576                                 // 64
#define WS_KERN   640                                 // 28800
#define WS_TD     29440                               // (unused now, keep layout)
#define WS_CANVAS (WS_TD + PLANES*PLANE_PX)
#define WS_POOL1  (WS_CANVAS + B_*CANVAS_PX)
#define WS_VF     (WS_POOL1 + B_*2*19*89)

__device__ __forceinline__ float sigmoidf_(float x) { return 1.f / (1.f + expf(-x)); }

// 4-px-wide 5-tap MAC into a float4 accumulator. WT must not be named 'w'.
#define ROW_MAC4(ACC, WT, A, Bv, C)                                           \
    ACC.x += WT[0]*A.z  + WT[1]*A.w  + WT[2]*Bv.x + WT[3]*Bv.y + WT[4]*Bv.z;  \
    ACC.y += WT[0]*A.w  + WT[1]*Bv.x + WT[2]*Bv.y + WT[3]*Bv.z + WT[4]*Bv.w;  \
    ACC.z += WT[0]*Bv.x + WT[1]*Bv.y + WT[2]*Bv.z + WT[3]*Bv.w + WT[4]*C.x;   \
    ACC.w += WT[0]*Bv.y + WT[1]*Bv.z + WT[2]*Bv.w + WT[3]*C.x  + WT[4]*C.y;

// both-channel MAC for kernel row KY (compile-time after unroll)
#define MACJ(ACC, KY) {                                                       \
    const float* wt0_ = wb0 + (KY)*5; const float* wt1_ = wb1 + (KY)*5;       \
    ROW_MAC4(ACC, wt0_, A0, B0, C0)                                           \
    ROW_MAC4(ACC, wt1_, A1, B1, C1) }

// ---------------------------------------------------------------------------
// Kernel 0: tiny precompute (filt_attn MLP+softmax, per-sample dyn kernels,
// nav softmax).  grid 16 (one block per batch), 256 threads.
// ---------------------------------------------------------------------------
__global__ __launch_bounds__(256)
void k_pre(const float* __restrict__ wctx, const float* __restrict__ dw1,
           const float* __restrict__ db1, const float* __restrict__ dw2,
           const float* __restrict__ db2, const float* __restrict__ dynf,
           const float* __restrict__ numnav, float* __restrict__ ws)
{
    const int tid = threadIdx.x;
    const int b = blockIdx.x;
    __shared__ float sh[128];
    __shared__ float sred[8];
    __shared__ float nv[36];
    __shared__ float nms[2];
    if (tid < 128) {
        float acc = db1[tid];
        for (int k = 0; k < HID_; ++k) acc += wctx[b*HID_ + k] * dw1[k*128 + tid];
        sh[tid] = fmaxf(acc, 0.f);
    }
    __syncthreads();
    if (tid < 4) {
        float acc = db2[tid];
        for (int j = 0; j < 128; ++j) acc += sh[j] * dw2[j*4 + tid];
        sred[tid] = acc;
    }
    __syncthreads();
    if (tid == 0) {
        float m = fmaxf(fmaxf(sred[0], sred[1]), fmaxf(sred[2], sred[3]));
        float e0 = expf(sred[0]-m), e1 = expf(sred[1]-m), e2 = expf(sred[2]-m), e3 = expf(sred[3]-m);
        float s = e0+e1+e2+e3;
        sred[4] = e0/s; sred[5] = e1/s; sred[6] = e2/s; sred[7] = e3/s;
        ws[WS_FATT + b*4+0] = sred[4]; ws[WS_FATT + b*4+1] = sred[5];
        ws[WS_FATT + b*4+2] = sred[6]; ws[WS_FATT + b*4+3] = sred[7];
    }
    __syncthreads();
    {
        const float fa0 = sred[4], fa1 = sred[5], fa2 = sred[6], fa3 = sred[7];
        for (int e = tid; e < 1800; e += 256) {
            float v = fa0*dynf[e] + fa1*dynf[1800+e] + fa2*dynf[3600+e] + fa3*dynf[5400+e];
            ws[WS_KERN + b*1800 + e] = v;
        }
    }
    if (tid < 36) nv[tid] = numnav[b*NAV_ + tid];
    __syncthreads();
    if (tid == 0) {
        float m = nv[0];
        for (int i = 1; i < 36; ++i) m = fmaxf(m, nv[i]);
        float s = 0.f;
        for (int i = 0; i < 36; ++i) s += expf(nv[i]-m);
        nms[0] = m; nms[1] = s;
    }
    __syncthreads();
    if (tid < 36) ws[WS_NAV + b*NAV_ + tid] = expf(nv[tid]-nms[0]) / nms[1];
}

// ---------------------------------------------------------------------------
// Kernel 1: FUSED conv1 + dynamic conv -> canvas.
// Block = (band, plane): stage d0/d1 band into LDS (zero-padded, each byte
// once) -> phase1: td into LDS (zero-padded) -> phase2: dyn conv from
// LDS-td + global obj -> canvas.  Threads process 4-row quads, 4-px wide.
// grid (6, 576), 256 threads.  LDS ~52.9 KB -> 3 blocks/CU.
// ---------------------------------------------------------------------------
__global__ __launch_bounds__(256)
void k_fused(const float* __restrict__ d0, const float* __restrict__ d1,
             const float* __restrict__ obj, const float* __restrict__ conv1_w,
             const float* __restrict__ conv1_b, float* __restrict__ ws)
{
    const int tid = threadIdx.x;
    const int band = blockIdx.x;      // 0..5
    const int plane = blockIdx.y;     // 0..575
    const int b = plane / NAV_;
    const int g = plane % NAV_;
    const int r0 = band * OUT_H;

    __shared__ __align__(16) float inL[2*IN_ROWS*LSTR];   // 36.7 KB
    __shared__ __align__(16) float tdL[TD_ROWS*LSTR];     // 15.7 KB
    __shared__ float swc[50];
    __shared__ float swk[50];
    __shared__ float sab[2];

    if (tid < 50)        swc[tid]     = conv1_w[g*50 + tid];
    else if (tid < 100)  swk[tid-50]  = ws[WS_KERN + plane*50 + (tid-50)];
    else if (tid == 100) sab[0]       = ws[WS_NAV + plane];
    else if (tid == 101) sab[1]       = conv1_b[g];

    const float4 z4 = make_float4(0.f, 0.f, 0.f, 0.f);

    // ---- stage: d0/d1 rows r0-4 .. r0+23, zero-padded (4-col left pad,
    //      out-of-image rows = 0).  2*28*41 float4 = 2296 tasks.
    for (int i = tid; i < 2*IN_ROWS*41; i += 256) {
        const int ch  = i / (IN_ROWS*41);
        const int rem = i % (IN_ROWS*41);
        const int row = rem / 41;
        const int c4  = rem % 41;
        const int gr  = r0 - 4 + row;
        float4 v = z4;
        if (c4 > 0 && (unsigned)gr < (unsigned)H_) {
            const float* sp = (ch == 0 ? d0 : d1) + (size_t)plane*PLANE_PX + gr*W_ + (c4*4 - 4);
            v = *(const float4*)sp;
        }
        *(float4*)&inL[(ch*IN_ROWS + row)*LSTR + c4*4] = v;
    }
    if (tid < TD_ROWS) *(float4*)&tdL[tid*LSTR] = z4;   // td left pads
    __syncthreads();

    // ---- phase 1: td quads (24 rows = 6 quads x 40 strips = 240 threads)
    if (tid < 240) {
        const int s = tid % 40;
        const int q = tid / 40;
        const int x0 = s*4;
        const bool hasR = s < 39;
        const float* wb0 = swc;
        const float* wb1 = swc + 25;
        float4 acc0 = z4, acc1 = z4, acc2 = z4, acc3 = z4;
        #pragma unroll
        for (int ir = 0; ir < 8; ++ir) {
            const float* p0 = &inL[(q*4 + ir)*LSTR + x0];
            const float* p1 = &inL[(IN_ROWS + q*4 + ir)*LSTR + x0];
            float4 A0 = *(const float4*)(p0);
            float4 B0 = *(const float4*)(p0 + 4);
            float4 C0 = hasR ? *(const float4*)(p0 + 8) : z4;
            float4 A1 = *(const float4*)(p1);
            float4 B1 = *(const float4*)(p1 + 4);
            float4 C1 = hasR ? *(const float4*)(p1 + 8) : z4;
            if (ir <= 4)            MACJ(acc0, ir)
            if (ir >= 1 && ir <= 5) MACJ(acc1, ir-1)
            if (ir >= 2 && ir <= 6) MACJ(acc2, ir-2)
            if (ir >= 3)            MACJ(acc3, ir-3)
        }
        const float bias = sab[1];
        #define WRITE_TD(J, ACC) {                                            \
            const int gtr = r0 - 2 + q*4 + (J);                               \
            const bool v_ = (unsigned)gtr < (unsigned)H_;                     \
            float4 o_ = v_ ? make_float4(ACC.x+bias, ACC.y+bias, ACC.z+bias,  \
                                         ACC.w+bias) : z4;                    \
            *(float4*)&tdL[(q*4 + (J))*LSTR + 4 + x0] = o_; }
        WRITE_TD(0, acc0) WRITE_TD(1, acc1) WRITE_TD(2, acc2) WRITE_TD(3, acc3)
        #undef WRITE_TD
    }
    __syncthreads();

    // ---- phase 2: dyn quads (20 rows = 5 quads x 40 strips = 200 threads)
    if (tid < 200) {
        const int s = tid % 40;
        const int q = tid / 40;
        const int x0 = s*4;
        const bool hasL = s > 0;
        const bool hasR = s < 39;
        const float* wb0 = swk;
        const float* wb1 = swk + 25;
        const float* op = obj + (size_t)plane*PLANE_PX;
        float4 acc0 = z4, acc1 = z4, acc2 = z4, acc3 = z4;
        #pragma unroll
        for (int ir = 0; ir < 8; ++ir) {
            const float* p0 = &tdL[(q*4 + ir)*LSTR + x0];
            float4 A0 = *(const float4*)(p0);
            float4 B0 = *(const float4*)(p0 + 4);
            float4 C0 = hasR ? *(const float4*)(p0 + 8) : z4;
            const int gr = r0 + q*4 - 2 + ir;
            const bool vy = (unsigned)gr < (unsigned)H_;
            const float* rp = op + gr*W_ + x0;
            float4 A1 = (vy && hasL) ? *(const float4*)(rp - 4) : z4;
            float4 B1 =  vy          ? *(const float4*)(rp)     : z4;
            float4 C1 = (vy && hasR) ? *(const float4*)(rp + 4) : z4;
            if (ir <= 4)            MACJ(acc0, ir)
            if (ir >= 1 && ir <= 5) MACJ(acc1, ir-1)
            if (ir >= 2 && ir <= 6) MACJ(acc2, ir-2)
            if (ir >= 3)            MACJ(acc3, ir-3)
        }
        const float a = sab[0];
        const int rowblk = 2 - g/12;
        const int colblk = g % 12;
        float* cbase = ws + WS_CANVAS + (size_t)b*CANVAS_PX + colblk*W_ + x0;
        #define WRITE_CV(J, ACC) {                                            \
            const int gor = r0 + q*4 + (J);                                   \
            *(float4*)(cbase + (size_t)(rowblk*H_ + gor)*CANVAS_W) =          \
                make_float4(a*ACC.x, a*ACC.y, a*ACC.z, a*ACC.w); }
        WRITE_CV(0, acc0) WRITE_CV(1, acc1) WRITE_CV(2, acc2) WRITE_CV(3, acc3)
        #undef WRITE_CV
    }
}

// ---------------------------------------------------------------------------
// Kernel 3: conv2_1 (k5, stride (5,7), dil 10) + avgpool3x3/3 -> pool1 (ws).
// One block per (b, version, pool-row a).  grid 608, 256 threads.
// ---------------------------------------------------------------------------
__global__ __launch_bounds__(256)
void k_conv2a(const float* __restrict__ w21p, const float* __restrict__ b21p,
              float* __restrict__ ws)
{
    const int blk = blockIdx.x;          // (b*2+ver)*19 + a
    const int a = blk % 19;
    const int bv = blk / 19;
    const int ver = bv & 1;
    const int b = bv >> 1;
    const int coloff = ver ? (CANVAS_W - W_) : 0;   // 1760

    __shared__ float s1[3*267];
    __shared__ float swt[25];
    if (threadIdx.x < 25) swt[threadIdx.x] = w21p[threadIdx.x];
    __syncthreads();
    const float b21 = b21p[0];
    const float* cv = ws + WS_CANVAS + (size_t)b*CANVAS_PX;

    for (int px = threadIdx.x; px < 3*267; px += 256) {
        const int row = px / 267;
        const int v = px % 267;
        const int u = 3*a + row;
        float acc = b21;
        #pragma unroll
        for (int ky = 0; ky < 5; ++ky) {
            const float* rp = cv + (5*u + 10*ky)*CANVAS_W;
            #pragma unroll
            for (int kx = 0; kx < 5; ++kx) {
                int c = 7*v + 10*kx + coloff;
                if (c >= CANVAS_W) c -= CANVAS_W;
                acc += swt[ky*5+kx] * rp[c];
            }
        }
        s1[px] = acc;
    }
    __syncthreads();
    if (threadIdx.x < 89) {
        const int bb = threadIdx.x;
        float s = 0.f;
        #pragma unroll
        for (int i = 0; i < 3; ++i)
            #pragma unroll
            for (int j = 0; j < 3; ++j)
                s += s1[i*267 + 3*bb + j];
        ws[WS_POOL1 + blk*89 + bb] = s * (1.f/9.f);
    }
}

// ---------------------------------------------------------------------------
// Kernel 4: conv2_2 + avgpool(3,9)/3 + v2 roll + combine + flip + softmax/10
// + mask.  One block per batch.  grid 16, 256 threads.
// ---------------------------------------------------------------------------
__global__ __launch_bounds__(256)
void k_conv2b(const float* __restrict__ w22p, const float* __restrict__ b22p,
              const int* __restrict__ navidx, float* __restrict__ ws,
              float* __restrict__ out)
{
    const int b = blockIdx.x;
    __shared__ float p[2*19*89];
    __shared__ float s2[2*9*43];
    __shared__ float svf[36];
    __shared__ float sms[2];
    __shared__ float swt[9];

    for (int i = threadIdx.x; i < 2*19*89; i += 256)
        p[i] = ws[WS_POOL1 + (b*2)*19*89 + i];
    if (threadIdx.x < 9) swt[threadIdx.x] = w22p[threadIdx.x];
    const float b22 = b22p[0];
    __syncthreads();

    for (int t = threadIdx.x; t < 2*9*43; t += 256) {
        const int ver = t / 387;
        const int r = t % 387;
        const int pp = r / 43;
        const int q = r % 43;
        float acc = b22;
        #pragma unroll
        for (int i = 0; i < 3; ++i)
            #pragma unroll
            for (int j = 0; j < 3; ++j)
                acc += swt[i*3+j] * p[(ver*19 + (2*pp+i))*89 + 2*q + 2*j];
        s2[ver*387 + pp*43 + q] = acc;
    }
    __syncthreads();

    if (threadIdx.x < 36) {
        const int gg = threadIdx.x;
        const int io = 2 - gg/12;
        const int j  = gg % 12;
        const int j2 = (j + 1) % 12;
        float s = 0.f;
        #pragma unroll
        for (int ii = 0; ii < 3; ++ii)
            #pragma unroll
            for (int jj = 0; jj < 9; ++jj)
                s += s2[(3*io+ii)*43 + 3*j + jj] + s2[387 + (3*io+ii)*43 + 3*j2 + jj];
        svf[gg] = s * (0.5f/27.f);
    }
    __syncthreads();
    if (threadIdx.x == 0) {
        float m = svf[0];
        for (int i = 1; i < 36; ++i) m = fmaxf(m, svf[i]);
        float s = 0.f;
        for (int i = 0; i < 36; ++i) s += expf((svf[i]-m)*0.1f);
        sms[0] = m; sms[1] = s;
    }
    __syncthreads();
    if (threadIdx.x < 36) {
        const float v = expf((svf[threadIdx.x]-sms[0])*0.1f) / sms[1];
        ws[WS_VF + b*36 + threadIdx.x] = v;
        out[16384 + b*36 + threadIdx.x] = v;
    }
    if (threadIdx.x < 37) {
        const int j = threadIdx.x;
        float v = (j == 0) ? 1.f : 0.f;
        #pragma unroll
        for (int t = 0; t < 8; ++t)
            if (navidx[b*8+t] + 1 == j) v = 1.f;
        out[16960 + b*37 + j] = v;
    }
}

// ---------------------------------------------------------------------------
// Kernel 5: LSTM GEMM + pointwise.  Block = 2 units x 4 gates x 16 batches,
// k split over 32 lanes.  grid 256, 256 threads.
// ---------------------------------------------------------------------------
#define CT_STRIDE 20
__global__ __launch_bounds__(256)
void k_lstm(const float* __restrict__ wctx, const float* __restrict__ pre_action,
            const float* __restrict__ h0, const float* __restrict__ c0,
            const float* __restrict__ w_ih, const float* __restrict__ w_hh,
            const float* __restrict__ b_ih, const float* __restrict__ b_hh,
            const float* __restrict__ ws, float* __restrict__ out)
{
    __shared__ float cT[1096*CT_STRIDE];
    __shared__ float red[8*32*16];
    __shared__ float gatev[8][16];
    const int tid = threadIdx.x;

    for (int idx = tid; idx < 1096*16; idx += 256) {
        const int k = idx >> 4;
        const int bb = idx & 15;
        float v;
        if (k < 512)       v = wctx[bb*512 + k];
        else if (k < 548)  v = ws[WS_VF + bb*36 + (k-512)];
        else if (k < 552)  v = ws[WS_FATT + bb*4 + (k-548)];
        else if (k < 584)  v = pre_action[bb*32 + (k-552)];
        else               v = h0[bb*512 + (k-584)];
        cT[k*CT_STRIDE + bb] = v;
    }
    __syncthreads();

    const int rl = tid >> 5;
    const int lane = tid & 31;
    const int u0 = blockIdx.x*2;
    const int ul = rl & 1;
    const int gate = rl >> 1;
    const int r = u0 + ul + gate*512;

    float acc[16];
    #pragma unroll
    for (int i = 0; i < 16; ++i) acc[i] = 0.f;

    const float* wih_r = w_ih + (size_t)r*584;
    for (int k = lane; k < 584; k += 32) {
        const float wv = wih_r[k];
        const float* cp = cT + k*CT_STRIDE;
        #pragma unroll
        for (int i = 0; i < 16; ++i) acc[i] += wv*cp[i];
    }
    const float* whh_r = w_hh + (size_t)r*512;
    for (int k = lane; k < 512; k += 32) {
        const float wv = whh_r[k];
        const float* cp = cT + (584+k)*CT_STRIDE;
        #pragma unroll
        for (int i = 0; i < 16; ++i) acc[i] += wv*cp[i];
    }
    float* rp = red + (rl*32 + lane)*16;
    #pragma unroll
    for (int i = 0; i < 16; ++i) rp[i] = acc[i];
    __syncthreads();

    if (tid < 128) {
        const int rr = tid >> 4;
        const int bb = tid & 15;
        const int rrow = u0 + (rr & 1) + (rr >> 1)*512;
        float s = b_ih[rrow] + b_hh[rrow];
        for (int l = 0; l < 32; ++l) s += red[(rr*32 + l)*16 + bb];
        gatev[rr][bb] = s;
    }
    __syncthreads();

    if (tid < 32) {
        const int ul2 = tid >> 4;
        const int bb = tid & 15;
        const int u = u0 + ul2;
        const float gi = gatev[0+ul2][bb];
        const float gf = gatev[2+ul2][bb];
        const float gg = gatev[4+ul2][bb];
        const float go = gatev[6+ul2][bb];
        const float c1 = sigmoidf_(gf)*c0[bb*512+u] + sigmoidf_(gi)*tanhf(gg);
        const float h1 = sigmoidf_(go)*tanhf(c1);
        out[bb*512 + u] = h1;
        out[8192 + bb*512 + u] = c1;
    }
}

// ---------------------------------------------------------------------------
extern "C" void kernel_launch(void* const* d_in, const int* in_sizes, int n_in,
                              void* d_out, int out_size, void* d_ws, size_t ws_size,
                              hipStream_t stream)
{
    const float* d0        = (const float*)d_in[0];
    const float* d1        = (const float*)d_in[1];
    const float* obj       = (const float*)d_in[2];
    const float* numnav    = (const float*)d_in[3];
    const float* preact    = (const float*)d_in[4];
    const float* h0        = (const float*)d_in[5];
    const float* c0        = (const float*)d_in[6];
    const float* wctx      = (const float*)d_in[7];
    const int*   navidx    = (const int*)d_in[8];
    const float* conv1_w   = (const float*)d_in[9];
    const float* conv1_b   = (const float*)d_in[10];
    const float* dynf      = (const float*)d_in[11];
    const float* dw1       = (const float*)d_in[12];
    const float* db1       = (const float*)d_in[13];
    const float* dw2       = (const float*)d_in[14];
    const float* db2       = (const float*)d_in[15];
    const float* w21       = (const float*)d_in[16];
    const float* b21       = (const float*)d_in[17];
    const float* w22       = (const float*)d_in[18];
    const float* b22       = (const float*)d_in[19];
    const float* wih       = (const float*)d_in[20];
    const float* whh       = (const float*)d_in[21];
    const float* bih       = (const float*)d_in[22];
    const float* bhh       = (const float*)d_in[23];
    float* ws  = (float*)d_ws;
    float* out = (float*)d_out;

    dim3 blk(256);
    k_pre   <<<dim3(16),      blk, 0, stream>>>(wctx, dw1, db1, dw2, db2, dynf, numnav, ws);
    k_fused <<<dim3(6, 576),  blk, 0, stream>>>(d0, d1, obj, conv1_w, conv1_b, ws);
    k_conv2a<<<dim3(608),     blk, 0, stream>>>(w21, b21, ws);
    k_conv2b<<<dim3(16),      blk, 0, stream>>>(w22, b22, navidx, ws, out);
    k_lstm  <<<dim3(256),     blk, 0, stream>>>(wctx, preact, h0, c0, wih, whh,
                                                bih, bhh, ws, out);
}